// Round 12
// baseline (54.160 us; speedup 1.0000x reference)
//
#include <hip/hip_runtime.h>

#define NB 32
#define NA 3
#define GD 52
#define GG 2704              // 52*52
#define NC 80
#define CHN 85               // NC + 5
#define CPW 16               // cells per wave (two 8-cell sub-passes)
#define CSW 8                // cells per sub-pass
#define WPP 169              // waves per plane = GG/CPW
#define NPLANE (NB * NA)     // 96
#define NWAVE (NPLANE * WPP) // 16224
#define WPB 2                // waves per block (128 threads)
#define NBLK (NWAVE / WPB)   // 8112
#define NXQ8 170             // CSW*CHN/4 x-quads per sub-pass
#define NTQ8 160             // CSW*NC/4 tcls quads per sub-pass
#define LXW 680              // CSW*CHN words per wave (reused across passes)
#define AUXW 144             // 9 aux planes * CPW per wave
#define RBLK 32              // stage-A reduce blocks
#define NEG_LN2_80 (-0.008664339757f)   // -ln2/80

typedef float __attribute__((ext_vector_type(4))) f32x4;

// sigmoid via hardware rcp (|z| < ~7 here; validated absmax 0.25 << 44.5)
__device__ __forceinline__ float sigm_u(float u) { return __builtin_amdgcn_rcpf(u); }

__global__ __launch_bounds__(128) void yolo_main(
    const float* __restrict__ x,
    const float* __restrict__ tx, const float* __restrict__ ty,
    const float* __restrict__ tw, const float* __restrict__ th,
    const float* __restrict__ tconf, const float* __restrict__ tcls,
    const float* __restrict__ sw1,
    const int* __restrict__ om, const int* __restrict__ nm,
    const int* __restrict__ imgdim,
    float* __restrict__ out,
    float4* __restrict__ partials,     // [NWAVE]; may be null
    double* __restrict__ accD)         // fallback padded atomics
{
    __shared__ float lx_all[WPB * LXW];    // per-wave 8-cell transposed tile
    __shared__ float la_all[WPB * AUXW];   // per-wave 16-cell aux tables

    const int tid  = threadIdx.x;
    const int widx = tid >> 6, lane = tid & 63;
    const int wid  = blockIdx.x * WPB + widx;
    const int plane = wid / WPP;
    const int sblk  = wid - plane * WPP;
    const int a = plane % NA, b = plane / NA;
    const int s0 = sblk * CPW;             // 64B-aligned x segment per channel
    float* lx = lx_all + widx * LXW;
    float* la = la_all + widx * AUXW;

    int iv = imgdim[0];
    float imgf = (iv > 0 && iv < 65536) ? (float)iv : __int_as_float(iv);
    const float stride = imgf / (float)GD;
    const float aw = (a == 0) ? 10.0f : ((a == 1) ? 16.0f : 33.0f);
    const float ah = (a == 0) ? 13.0f : ((a == 1) ? 30.0f : 23.0f);

    const long pbase = (long)plane * GG + s0;
    const float* xb = x + ((long)b * (NA * CHN) + a * CHN) * GG + s0;
    const float* tb = tcls + pbase * NC;

    // ---- issue ALL x loads up front: both sub-tiles (6 KB/wave in flight) ----
    float4 xrA[3], xrB[3];
    #pragma unroll
    for (int k = 0; k < 3; ++k) {
        int p = lane + 64 * k;
        if (p < NXQ8) {
            int ch = p >> 1, sq = (p & 1) << 2;
            xrA[k] = *(const float4*)(xb + (long)ch * GG + sq);
            xrB[k] = *(const float4*)(xb + (long)ch * GG + CSW + sq);
        }
    }

    // ---- aux in registers, replicated x4 (lane holds cell lane&15) ----
    const int sc = lane & 15;
    float r_tx = tx[pbase + sc], r_ty = ty[pbase + sc];
    float r_tw = tw[pbase + sc], r_th = th[pbase + sc];
    float r_tc = tconf[pbase + sc], r_sw = sw1[pbase + sc];
    float r_om = (float)om[pbase + sc], r_nm = (float)nm[pbase + sc];

    // ---- la table: 9 planes x 16 cells (lanes 0-15 write) ----
    //      planes: 0:tx 1:ty 2:tw 3:th 4:tconf 5:om*sw 6:nm 7:gx 8:gy
    if (lane < CPW) {
        int gcell = s0 + lane;
        int gyi = gcell / GD;
        la[0 * CPW + lane] = r_tx;  la[1 * CPW + lane] = r_ty;
        la[2 * CPW + lane] = r_tw;  la[3 * CPW + lane] = r_th;
        la[4 * CPW + lane] = r_tc;  la[5 * CPW + lane] = r_om * r_sw;
        la[6 * CPW + lane] = r_nm;
        la[7 * CPW + lane] = (float)(gcell - gyi * GD);
        la[8 * CPW + lane] = (float)gyi;
    }
    __builtin_amdgcn_wave_barrier();

    float s_obj = 0.f, s_cn = 0.f, s_cl2 = 0.f;
    float4 tr[3]; float gk[3];

// gate + issue tcls loads for sub-pass P (uniform-flow shfl: exec-mask-safe)
#define TCLS_ISSUE(P)                                                          \
    _Pragma("unroll")                                                          \
    for (int k = 0; k < 3; ++k) {                                              \
        gk[k] = 0.0f;                                                          \
        int q = lane + 64 * k;                                                 \
        if (q < NTQ8) {                                                        \
            int s = q / 20, c4 = (q - s * 20) * 4;                             \
            float g = __shfl(r_om, (P) * CSW + s, 16);                         \
            gk[k] = g;                                                         \
            if (g != 0.0f)                                                     \
                tr[k] = *(const float4*)(tb + ((P) * CSW + s) * NC + c4);      \
        }                                                                      \
    }

// transform sub-pass P from XR regs into lx (8-cell, [s][ch] flat)
#define TRANSFORM(P, XR)                                                       \
    _Pragma("unroll")                                                          \
    for (int k = 0; k < 3; ++k) {                                              \
        int q = lane + 64 * k;                                                 \
        if (q >= NXQ8) continue;                                               \
        int ch = q >> 1, sq = (q & 1) << 2;                                    \
        float vv[4] = { XR[k].x, XR[k].y, XR[k].z, XR[k].w };                  \
        if (ch >= 5) {                                                         \
            _Pragma("unroll")                                                  \
            for (int j = 0; j < 4; ++j)                                        \
                lx[(sq + j) * CHN + ch] = sigm_u(1.0f + __expf(-vv[j]));       \
        } else if (ch == 0) {                                                  \
            _Pragma("unroll")                                                  \
            for (int j = 0; j < 4; ++j) {                                      \
                int s = sq + j, sa = (P) * CSW + s;                            \
                float p = sigm_u(1.0f + __expf(-vv[j]));                       \
                float d = p - la[0 * CPW + sa];                                \
                s_obj = fmaf(la[5 * CPW + sa], d * d, s_obj);                  \
                lx[s * CHN + 0] = (p + la[7 * CPW + sa]) * stride;             \
            }                                                                  \
        } else if (ch == 1) {                                                  \
            _Pragma("unroll")                                                  \
            for (int j = 0; j < 4; ++j) {                                      \
                int s = sq + j, sa = (P) * CSW + s;                            \
                float p = sigm_u(1.0f + __expf(-vv[j]));                       \
                float d = p - la[1 * CPW + sa];                                \
                s_obj = fmaf(la[5 * CPW + sa], d * d, s_obj);                  \
                lx[s * CHN + 1] = (p + la[8 * CPW + sa]) * stride;             \
            }                                                                  \
        } else if (ch == 2) {                                                  \
            _Pragma("unroll")                                                  \
            for (int j = 0; j < 4; ++j) {                                      \
                int s = sq + j, sa = (P) * CSW + s;                            \
                float d = vv[j] - la[2 * CPW + sa];                            \
                s_obj = fmaf(la[5 * CPW + sa], d * d, s_obj);                  \
                lx[s * CHN + 2] = __expf(vv[j]) * aw;                          \
            }                                                                  \
        } else if (ch == 3) {                                                  \
            _Pragma("unroll")                                                  \
            for (int j = 0; j < 4; ++j) {                                      \
                int s = sq + j, sa = (P) * CSW + s;                            \
                float d = vv[j] - la[3 * CPW + sa];                            \
                s_obj = fmaf(la[5 * CPW + sa], d * d, s_obj);                  \
                lx[s * CHN + 3] = __expf(vv[j]) * ah;                          \
            }                                                                  \
        } else {                                                               \
            _Pragma("unroll")                                                  \
            for (int j = 0; j < 4; ++j) {                                      \
                int s = sq + j, sa = (P) * CSW + s;                            \
                float z = vv[j];                                               \
                float u = 1.0f + __expf(-z);                                   \
                float p = sigm_u(u);                                           \
                float t = la[4 * CPW + sa];                                    \
                float bb = fmaf(1.0f - t, z, __logf(u));                       \
                s_obj = fmaf(la[5 * CPW + sa], bb, s_obj);                     \
                s_cn  = fmaf(la[6 * CPW + sa], bb, s_cn);                      \
                lx[s * CHN + 4] = p;                                           \
            }                                                                  \
        }                                                                      \
    }

// store-out sub-pass P: ds_read_b128 + NON-TEMPORAL coalesced 16B stores
// (out is write-once, never read -> keep it out of L2/L3 so x/tcls stay hot)
#define STORE_OUT(P)                                                           \
    {                                                                          \
        float* ob = out + (pbase + (P) * CSW) * CHN;                           \
        _Pragma("unroll")                                                      \
        for (int k = 0; k < 3; ++k) {                                          \
            int q = lane + 64 * k;                                             \
            if (q < NXQ8) {                                                    \
                float4 w4 = *(const float4*)&lx[4 * q];                        \
                f32x4 wv = { w4.x, w4.y, w4.z, w4.w };                         \
                __builtin_nontemporal_store(wv, (f32x4*)(ob + 4 * q));         \
            }                                                                  \
        }                                                                      \
    }

// cls BCE sub-pass (log2 form), from tr/gk + lx reads
#define CLS_BCE()                                                              \
    _Pragma("unroll")                                                          \
    for (int k = 0; k < 3; ++k) {                                              \
        if (gk[k] != 0.0f) {                                                   \
            int q = lane + 64 * k;                                             \
            int s = q / 20, c4 = (q - s * 20) * 4;                             \
            int base = s * CHN + 5 + c4;                                       \
            float tt[4] = { tr[k].x, tr[k].y, tr[k].z, tr[k].w };              \
            _Pragma("unroll")                                                  \
            for (int j = 0; j < 4; ++j) {                                      \
                float p  = lx[base + j];                                       \
                float l0 = __log2f(p);                                         \
                float l1 = __log2f(1.0f - p);                                  \
                s_cl2 += fmaf(tt[j], l0 - l1, l1);                             \
            }                                                                  \
        }                                                                      \
    }

    // ---- sub-pass A ----
    TCLS_ISSUE(0)
    TRANSFORM(0, xrA)
    __builtin_amdgcn_wave_barrier();
    STORE_OUT(0)
    CLS_BCE()
    __builtin_amdgcn_wave_barrier();

    // ---- sub-pass B (lx reuse safe: same-wave DS ops are in-order) ----
    TCLS_ISSUE(1)
    TRANSFORM(1, xrB)
    __builtin_amdgcn_wave_barrier();
    STORE_OUT(1)
    CLS_BCE()

    // loss_cls contribution: (-ln2 * s_cl2 / 80) / n_obj, folded into s_obj
    s_obj = fmaf(s_cl2, NEG_LN2_80, s_obj);

    // ---- wave-level reduction only; one float4 row per wave ----
    float v0 = (lane < CPW) ? r_om : 0.0f;   // replicated x4: count once
    float v1 = (lane < CPW) ? r_nm : 0.0f;
    float v2 = s_obj, v3 = s_cn;
    #pragma unroll
    for (int off = 32; off > 0; off >>= 1) {
        v0 += __shfl_down(v0, off, 64);
        v1 += __shfl_down(v1, off, 64);
        v2 += __shfl_down(v2, off, 64);
        v3 += __shfl_down(v3, off, 64);
    }
    if (lane == 0) {
        if (partials) {
            partials[wid] = make_float4(v0, v1, v2, v3);
        } else {
            atomicAdd(&accD[0], (double)v0);
            atomicAdd(&accD[8], (double)v1);
            atomicAdd(&accD[16], (double)v2);
            atomicAdd(&accD[24], (double)v3);
        }
    }
}

// stage A: RBLK blocks, each reduces a grid-stride slice -> stage2[bid]
__global__ __launch_bounds__(256) void yolo_reduceA(const float4* __restrict__ partials,
                                                    float4* __restrict__ stage2)
{
    __shared__ float sred[4][4];
    const int tid = threadIdx.x, wv = tid >> 6, ln = tid & 63;
    float d0 = 0, d1 = 0, d2 = 0, d3 = 0;
    for (int i = blockIdx.x * 256 + tid; i < NWAVE; i += RBLK * 256) {
        float4 p = partials[i];
        d0 += p.x; d1 += p.y; d2 += p.z; d3 += p.w;
    }
    #pragma unroll
    for (int off = 32; off > 0; off >>= 1) {
        d0 += __shfl_down(d0, off, 64);
        d1 += __shfl_down(d1, off, 64);
        d2 += __shfl_down(d2, off, 64);
        d3 += __shfl_down(d3, off, 64);
    }
    if (ln == 0) { sred[wv][0] = d0; sred[wv][1] = d1; sred[wv][2] = d2; sred[wv][3] = d3; }
    __syncthreads();
    if (tid == 0)
        stage2[blockIdx.x] = make_float4(sred[0][0] + sred[1][0] + sred[2][0] + sred[3][0],
                                         sred[0][1] + sred[1][1] + sred[2][1] + sred[3][1],
                                         sred[0][2] + sred[1][2] + sred[2][2] + sred[3][2],
                                         sred[0][3] + sred[1][3] + sred[2][3] + sred[3][3]);
}

// stage B: one wave folds the RBLK rows and finalizes the loss
__global__ __launch_bounds__(64) void yolo_reduceB(const float4* __restrict__ stage2,
                                                   float* __restrict__ out_loss)
{
    const int ln = threadIdx.x;
    double d0 = 0, d1 = 0, d2 = 0, d3 = 0;
    if (ln < RBLK) {
        float4 p = stage2[ln];
        d0 = p.x; d1 = p.y; d2 = p.z; d3 = p.w;
    }
    #pragma unroll
    for (int off = 32; off > 0; off >>= 1) {
        d0 += __shfl_down(d0, off, 64);
        d1 += __shfl_down(d1, off, 64);
        d2 += __shfl_down(d2, off, 64);
        d3 += __shfl_down(d3, off, 64);
    }
    if (ln == 0) {
        double nobj = fmax(d0, 1.0), nnoobj = fmax(d1, 1.0);
        *out_loss = (float)(d2 / nobj + 100.0 * d3 / nnoobj);
    }
}

__global__ void yolo_final_atomic(const double* __restrict__ accD, float* __restrict__ out_loss)
{
    double nobj = fmax(accD[0], 1.0), nnoobj = fmax(accD[8], 1.0);
    *out_loss = (float)(accD[16] / nobj + 100.0 * accD[24] / nnoobj);
}

extern "C" void kernel_launch(void* const* d_in, const int* in_sizes, int n_in,
                              void* d_out, int out_size, void* d_ws, size_t ws_size,
                              hipStream_t stream)
{
    const float* x     = (const float*)d_in[0];
    const float* tx    = (const float*)d_in[1];
    const float* ty    = (const float*)d_in[2];
    const float* tw    = (const float*)d_in[3];
    const float* th    = (const float*)d_in[4];
    const float* tconf = (const float*)d_in[5];
    const float* tcls  = (const float*)d_in[6];
    const float* sw1   = (const float*)d_in[7];
    const int*   om    = (const int*)d_in[8];
    const int*   nm    = (const int*)d_in[9];
    const int*   img   = (const int*)d_in[10];
    float* out = (float*)d_out;

    const size_t need = (size_t)(NWAVE + RBLK) * sizeof(float4);  // ~260 KB
    dim3 grid(NBLK);   // 8112 blocks of 128 threads

    if (ws_size >= need) {
        float4* partials = (float4*)d_ws;
        float4* stage2   = partials + NWAVE;
        yolo_main<<<grid, 128, 0, stream>>>(x, tx, ty, tw, th, tconf, tcls, sw1,
                                            om, nm, img, out, partials, nullptr);
        yolo_reduceA<<<RBLK, 256, 0, stream>>>(partials, stage2);
        yolo_reduceB<<<1, 64, 0, stream>>>(stage2, out + (out_size - 1));
    } else {
        double* accD = (double*)d_ws;
        hipMemsetAsync(d_ws, 0, 32 * sizeof(double), stream);
        yolo_main<<<grid, 128, 0, stream>>>(x, tx, ty, tw, th, tconf, tcls, sw1,
                                            om, nm, img, out, nullptr, accD);
        yolo_final_atomic<<<1, 1, 0, stream>>>(accD, out + (out_size - 1));
    }
}

// Round 13
// 53.920 us; speedup vs baseline: 1.0045x; 1.0045x over previous
//
#include <hip/hip_runtime.h>

#define NB 32
#define NA 3
#define GD 52
#define GG 2704              // 52*52
#define NC 80
#define CHN 85               // NC + 5
#define CPW 16               // cells per wave
#define WPP 169              // waves per plane = GG/CPW
#define NPLANE (NB * NA)     // 96
#define NWAVE (NPLANE * WPP) // 16224
#define WPB 2                // waves per block (128 threads)
#define NBLK (NWAVE / WPB)   // 8112
#define NXQ 340              // CPW*CHN/4 x-quads per wave
#define LXW 1360             // CPW*CHN words per wave
#define AUXW 160             // 10 aux planes * CPW per wave
#define RBLK 32              // stage-A reduce blocks
#define LN2_80 (0.008664339757f)        // ln2/80
#define INV_LN2 (1.4426950408889634f)

// sigmoid via hardware rcp (|z| < ~7 here; validated absmax 0.25 << 44.5)
__device__ __forceinline__ float sigm_u(float u) { return __builtin_amdgcn_rcpf(u); }

__global__ __launch_bounds__(128) void yolo_main(
    const float* __restrict__ x,
    const float* __restrict__ tx, const float* __restrict__ ty,
    const float* __restrict__ tw, const float* __restrict__ th,
    const float* __restrict__ tconf, const float* __restrict__ tcls,
    const float* __restrict__ sw1,
    const int* __restrict__ om, const int* __restrict__ nm,
    const int* __restrict__ imgdim,
    float* __restrict__ out,
    float4* __restrict__ partials,     // [NWAVE]; may be null
    double* __restrict__ accD)         // fallback padded atomics
{
    __shared__ float lx_all[WPB * LXW];    // per-wave 16-cell transposed tile
    __shared__ float la_all[WPB * AUXW];   // per-wave aux tables

    const int tid  = threadIdx.x;
    const int widx = tid >> 6, lane = tid & 63;
    const int wid  = blockIdx.x * WPB + widx;
    const int plane = wid / WPP;
    const int sblk  = wid - plane * WPP;
    const int a = plane % NA, b = plane / NA;
    const int s0 = sblk * CPW;             // 64B-aligned x segment per channel
    float* lx = lx_all + widx * LXW;
    float* la = la_all + widx * AUXW;

    int iv = imgdim[0];
    float imgf = (iv > 0 && iv < 65536) ? (float)iv : __int_as_float(iv);
    const float stride = imgf / (float)GD;
    const float aw = (a == 0) ? 10.0f : ((a == 1) ? 16.0f : 33.0f);
    const float ah = (a == 0) ? 13.0f : ((a == 1) ? 30.0f : 23.0f);

    const long pbase = (long)plane * GG + s0;
    const float* xb = x + ((long)b * (NA * CHN) + a * CHN) * GG + s0;
    const float* tb = tcls + pbase * NC;

    // ---- issue ALL x loads up front (6 KB/wave in flight) ----
    float4 xr[6];
    #pragma unroll
    for (int k = 0; k < 6; ++k) {
        int q = lane + 64 * k;
        if (q < NXQ) {
            int ch = q >> 2, sq = (q & 3) << 2;   // 4 quads per channel
            xr[k] = *(const float4*)(xb + (long)ch * GG + sq);
        }
    }

    // ---- aux in registers, replicated x4 (lane holds cell lane&15) ----
    const int sc = lane & 15;
    float r_tx = tx[pbase + sc], r_ty = ty[pbase + sc];
    float r_tw = tw[pbase + sc], r_th = th[pbase + sc];
    float r_tc = tconf[pbase + sc], r_sw = sw1[pbase + sc];
    float r_om = (float)om[pbase + sc], r_nm = (float)nm[pbase + sc];

    // ---- la table: 10 planes x 16 cells (lanes 0-15 write) ----
    //      0:tx 1:ty 2:tw 3:th 4:tconf 5:om*sw 6:nm 7:gx 8:gy 9:om
    if (lane < CPW) {
        int gcell = s0 + lane;
        int gyi = gcell / GD;
        la[0 * CPW + lane] = r_tx;  la[1 * CPW + lane] = r_ty;
        la[2 * CPW + lane] = r_tw;  la[3 * CPW + lane] = r_th;
        la[4 * CPW + lane] = r_tc;  la[5 * CPW + lane] = r_om * r_sw;
        la[6 * CPW + lane] = r_nm;
        la[7 * CPW + lane] = (float)(gcell - gyi * GD);
        la[8 * CPW + lane] = (float)gyi;
        la[9 * CPW + lane] = r_om;
    }
    __builtin_amdgcn_wave_barrier();

    float s_obj = 0.f, s_cn = 0.f, s_cl2 = 0.f;
    float tA[4], tB[4];

// prefetch the 4 gated tcls scalars for group K into T (0 when gated off ->
// mul-gate later can't produce NaN). Per-lane loads from one 64B line are
// merged by the wave coalescer. LDS om-read is per-lane-address: exec-safe.
#define TPREF(K, T)                                                            \
    {                                                                          \
        int q = lane + 64 * (K);                                               \
        int ch = q >> 2, sq = (q & 3) << 2;                                    \
        _Pragma("unroll")                                                      \
        for (int j = 0; j < 4; ++j) {                                          \
            T[j] = 0.0f;                                                       \
            int s = sq + j;                                                    \
            if (q < NXQ && ch >= 5 && la[9 * CPW + s] != 0.0f)                 \
                T[j] = tb[s * NC + (ch - 5)];                                  \
        }                                                                      \
    }

// transform group K: activation + LDS store + ALL losses fused (cls BCE from
// logits: bce = ln u + (1-t) z, u = 1+e^-z, since p = 1/u)
#define XFORM(K, T)                                                            \
    {                                                                          \
        int q = lane + 64 * (K);                                               \
        if (q < NXQ) {                                                         \
            int ch = q >> 2, sq = (q & 3) << 2;                                \
            float vv[4] = { xr[K].x, xr[K].y, xr[K].z, xr[K].w };              \
            if (ch >= 5) {                                                     \
                _Pragma("unroll")                                              \
                for (int j = 0; j < 4; ++j) {                                  \
                    int s = sq + j;                                            \
                    float z = vv[j];                                           \
                    float u = 1.0f + __expf(-z);                               \
                    lx[s * CHN + ch] = sigm_u(u);                              \
                    float o = la[9 * CPW + s];                                 \
                    float e = fmaf(1.0f - T[j], z * INV_LN2, __log2f(u));      \
                    s_cl2 = fmaf(o, e, s_cl2);                                 \
                }                                                              \
            } else if (ch == 0) {                                              \
                _Pragma("unroll")                                              \
                for (int j = 0; j < 4; ++j) {                                  \
                    int s = sq + j;                                            \
                    float p = sigm_u(1.0f + __expf(-vv[j]));                   \
                    float d = p - la[0 * CPW + s];                             \
                    s_obj = fmaf(la[5 * CPW + s], d * d, s_obj);               \
                    lx[s * CHN + 0] = (p + la[7 * CPW + s]) * stride;          \
                }                                                              \
            } else if (ch == 1) {                                              \
                _Pragma("unroll")                                              \
                for (int j = 0; j < 4; ++j) {                                  \
                    int s = sq + j;                                            \
                    float p = sigm_u(1.0f + __expf(-vv[j]));                   \
                    float d = p - la[1 * CPW + s];                             \
                    s_obj = fmaf(la[5 * CPW + s], d * d, s_obj);               \
                    lx[s * CHN + 1] = (p + la[8 * CPW + s]) * stride;          \
                }                                                              \
            } else if (ch == 2) {                                              \
                _Pragma("unroll")                                              \
                for (int j = 0; j < 4; ++j) {                                  \
                    int s = sq + j;                                            \
                    float d = vv[j] - la[2 * CPW + s];                         \
                    s_obj = fmaf(la[5 * CPW + s], d * d, s_obj);               \
                    lx[s * CHN + 2] = __expf(vv[j]) * aw;                      \
                }                                                              \
            } else if (ch == 3) {                                              \
                _Pragma("unroll")                                              \
                for (int j = 0; j < 4; ++j) {                                  \
                    int s = sq + j;                                            \
                    float d = vv[j] - la[3 * CPW + s];                         \
                    s_obj = fmaf(la[5 * CPW + s], d * d, s_obj);               \
                    lx[s * CHN + 3] = __expf(vv[j]) * ah;                      \
                }                                                              \
            } else { /* ch == 4: conf BCE from logits */                       \
                _Pragma("unroll")                                              \
                for (int j = 0; j < 4; ++j) {                                  \
                    int s = sq + j;                                            \
                    float z = vv[j];                                           \
                    float u = 1.0f + __expf(-z);                               \
                    float p = sigm_u(u);                                       \
                    float t = la[4 * CPW + s];                                 \
                    float bb = fmaf(1.0f - t, z, __logf(u));                   \
                    s_obj = fmaf(la[5 * CPW + s], bb, s_obj);                  \
                    s_cn  = fmaf(la[6 * CPW + s], bb, s_cn);                   \
                    lx[s * CHN + 4] = p;                                       \
                }                                                              \
            }                                                                  \
        }                                                                      \
    }

    // ---- software-pipelined transform: t-loads issued 2 groups ahead ----
    TPREF(0, tA)
    TPREF(1, tB)
    XFORM(0, tA)
    TPREF(2, tA)
    XFORM(1, tB)
    TPREF(3, tB)
    XFORM(2, tA)
    TPREF(4, tA)
    XFORM(3, tB)
    TPREF(5, tB)
    XFORM(4, tA)
    XFORM(5, tB)
    __builtin_amdgcn_wave_barrier();

    // ---- output: wave-local ds_read_b128 + coalesced 16B global stores ----
    float* ob = out + pbase * CHN;
    #pragma unroll
    for (int k = 0; k < 6; ++k) {
        int q = lane + 64 * k;
        if (q < NXQ) {
            float4 w4 = *(const float4*)&lx[4 * q];
            *(float4*)(ob + 4 * q) = w4;
        }
    }

    // loss_cls contribution: (ln2 * s_cl2 / 80) / n_obj, folded into s_obj
    s_obj = fmaf(s_cl2, LN2_80, s_obj);

    // ---- wave-level reduction only; one float4 row per wave ----
    float v0 = (lane < CPW) ? r_om : 0.0f;   // replicated x4: count once
    float v1 = (lane < CPW) ? r_nm : 0.0f;
    float v2 = s_obj, v3 = s_cn;
    #pragma unroll
    for (int off = 32; off > 0; off >>= 1) {
        v0 += __shfl_down(v0, off, 64);
        v1 += __shfl_down(v1, off, 64);
        v2 += __shfl_down(v2, off, 64);
        v3 += __shfl_down(v3, off, 64);
    }
    if (lane == 0) {
        if (partials) {
            partials[wid] = make_float4(v0, v1, v2, v3);
        } else {
            atomicAdd(&accD[0], (double)v0);
            atomicAdd(&accD[8], (double)v1);
            atomicAdd(&accD[16], (double)v2);
            atomicAdd(&accD[24], (double)v3);
        }
    }
}

// stage A: RBLK blocks, each reduces a grid-stride slice -> stage2[bid]
__global__ __launch_bounds__(256) void yolo_reduceA(const float4* __restrict__ partials,
                                                    float4* __restrict__ stage2)
{
    __shared__ float sred[4][4];
    const int tid = threadIdx.x, wv = tid >> 6, ln = tid & 63;
    float d0 = 0, d1 = 0, d2 = 0, d3 = 0;
    for (int i = blockIdx.x * 256 + tid; i < NWAVE; i += RBLK * 256) {
        float4 p = partials[i];
        d0 += p.x; d1 += p.y; d2 += p.z; d3 += p.w;
    }
    #pragma unroll
    for (int off = 32; off > 0; off >>= 1) {
        d0 += __shfl_down(d0, off, 64);
        d1 += __shfl_down(d1, off, 64);
        d2 += __shfl_down(d2, off, 64);
        d3 += __shfl_down(d3, off, 64);
    }
    if (ln == 0) { sred[wv][0] = d0; sred[wv][1] = d1; sred[wv][2] = d2; sred[wv][3] = d3; }
    __syncthreads();
    if (tid == 0)
        stage2[blockIdx.x] = make_float4(sred[0][0] + sred[1][0] + sred[2][0] + sred[3][0],
                                         sred[0][1] + sred[1][1] + sred[2][1] + sred[3][1],
                                         sred[0][2] + sred[1][2] + sred[2][2] + sred[3][2],
                                         sred[0][3] + sred[1][3] + sred[2][3] + sred[3][3]);
}

// stage B: one wave folds the RBLK rows and finalizes the loss
__global__ __launch_bounds__(64) void yolo_reduceB(const float4* __restrict__ stage2,
                                                   float* __restrict__ out_loss)
{
    const int ln = threadIdx.x;
    double d0 = 0, d1 = 0, d2 = 0, d3 = 0;
    if (ln < RBLK) {
        float4 p = stage2[ln];
        d0 = p.x; d1 = p.y; d2 = p.z; d3 = p.w;
    }
    #pragma unroll
    for (int off = 32; off > 0; off >>= 1) {
        d0 += __shfl_down(d0, off, 64);
        d1 += __shfl_down(d1, off, 64);
        d2 += __shfl_down(d2, off, 64);
        d3 += __shfl_down(d3, off, 64);
    }
    if (ln == 0) {
        double nobj = fmax(d0, 1.0), nnoobj = fmax(d1, 1.0);
        *out_loss = (float)(d2 / nobj + 100.0 * d3 / nnoobj);
    }
}

__global__ void yolo_final_atomic(const double* __restrict__ accD, float* __restrict__ out_loss)
{
    double nobj = fmax(accD[0], 1.0), nnoobj = fmax(accD[8], 1.0);
    *out_loss = (float)(accD[16] / nobj + 100.0 * accD[24] / nnoobj);
}

extern "C" void kernel_launch(void* const* d_in, const int* in_sizes, int n_in,
                              void* d_out, int out_size, void* d_ws, size_t ws_size,
                              hipStream_t stream)
{
    const float* x     = (const float*)d_in[0];
    const float* tx    = (const float*)d_in[1];
    const float* ty    = (const float*)d_in[2];
    const float* tw    = (const float*)d_in[3];
    const float* th    = (const float*)d_in[4];
    const float* tconf = (const float*)d_in[5];
    const float* tcls  = (const float*)d_in[6];
    const float* sw1   = (const float*)d_in[7];
    const int*   om    = (const int*)d_in[8];
    const int*   nm    = (const int*)d_in[9];
    const int*   img   = (const int*)d_in[10];
    float* out = (float*)d_out;

    const size_t need = (size_t)(NWAVE + RBLK) * sizeof(float4);  // ~260 KB
    dim3 grid(NBLK);   // 8112 blocks of 128 threads

    if (ws_size >= need) {
        float4* partials = (float4*)d_ws;
        float4* stage2   = partials + NWAVE;
        yolo_main<<<grid, 128, 0, stream>>>(x, tx, ty, tw, th, tconf, tcls, sw1,
                                            om, nm, img, out, partials, nullptr);
        yolo_reduceA<<<RBLK, 256, 0, stream>>>(partials, stage2);
        yolo_reduceB<<<1, 64, 0, stream>>>(stage2, out + (out_size - 1));
    } else {
        double* accD = (double*)d_ws;
        hipMemsetAsync(d_ws, 0, 32 * sizeof(double), stream);
        yolo_main<<<grid, 128, 0, stream>>>(x, tx, ty, tw, th, tconf, tcls, sw1,
                                            om, nm, img, out, nullptr, accD);
        yolo_final_atomic<<<1, 1, 0, stream>>>(accD, out + (out_size - 1));
    }
}